// Round 13
// baseline (140.199 us; speedup 1.0000x reference)
//
#include <hip/hip_runtime.h>
#include <hip/hip_bf16.h>
#include <stdint.h>

#define B_DIM   4096
#define IN_DIM  512
#define OUT_DIM 512
#define M_DIM   16
#define K_DIM   (IN_DIM * M_DIM)     // 8192
#define MN      (B_DIM * OUT_DIM)    // 2097152

// basis interpolation table: 512 intervals over [0.1, 10], stride 20 f32 (bank spread)
#define TBL_N    512
#define TBL_STR  20
#define TBL_F32  ((TBL_N + 1) * TBL_STR)   // 10260 floats = 41040 B
#define TBL_H    (9.9f / (float)TBL_N)
#define TBL_INVH ((float)TBL_N / 9.9f)

typedef unsigned short ushort_t;
typedef __attribute__((ext_vector_type(8))) __bf16 bf16x8;
typedef __attribute__((ext_vector_type(2))) __bf16 bf16x2;
typedef __attribute__((ext_vector_type(4))) float  f32x4;

__device__ __forceinline__ ushort_t f2bf(float f) {
  union { float f; uint32_t u; } v; v.f = f;
  uint32_t u = v.u + 0x7fffu + ((v.u >> 16) & 1u);   // RNE
  return (ushort_t)(u >> 16);
}

// pack two floats -> one u32 of 2 x bf16 (compiler emits v_cvt_pk_bf16_f32)
__device__ __forceinline__ uint32_t pkbf(float lo, float hi) {
  union { bf16x2 h; uint32_t u; } v;
  v.h[0] = (__bf16)lo; v.h[1] = (__bf16)hi;
  return v.u;
}

// ---------- phase 1: coeffs fp32 -> bf16  +  basis table build ----------
#define CONV_N4     (OUT_DIM * K_DIM / 4)
#define CONV_BLOCKS (CONV_N4 / 256)     // 4096
__global__ __launch_bounds__(256) void convert_coeffs_kernel(
    const float* __restrict__ src, ushort_t* __restrict__ dst,
    const float* __restrict__ bc, float* __restrict__ tG) {
  const int blk = blockIdx.x, tid = threadIdx.x;
  if (blk < CONV_BLOCKS) {
    int i = blk * 256 + tid;
    float4 v = ((const float4*)src)[i];
    ushort4 o;
    o.x = f2bf(v.x); o.y = f2bf(v.y); o.z = f2bf(v.z); o.w = f2bf(v.w);
    ((ushort4*)dst)[i] = o;
    return;
  }
  // table block: T[e][m] = f_m(0.1 + e*h), e in [0,512] — exact same math the
  // fused kernel used through r9..r12 (bf16-validated), full f32 precision.
  const float LOG2E = 1.44269504088896340736f;
  const float LN2   = 0.69314718055994530942f;
  for (int e = tid; e <= TBL_N; e += 256) {
    float xv = 0.1f + (float)e * TBL_H;
    float xl2 = xv * LOG2E;
    float x2 = xv * xv, x3 = x2 * xv, x4 = x2 * x2;
    #pragma unroll
    for (int m = 0; m < M_DIM; ++m) {
      float b1 = bc[m*8+0], b2 = bc[m*8+1], b3 = bc[m*8+2], b4 = bc[m*8+3];
      float b5 = bc[m*8+4], b6 = bc[m*8+5], b7 = bc[m*8+6], b8 = bc[m*8+7];
      float e2    = __builtin_amdgcn_exp2f(b3 * xl2);
      float inner = e2 - 1.0f;                                  // expm1(b3 x) > 0
      float p     = __builtin_amdgcn_exp2f(b4 * __builtin_amdgcn_logf(inner));
      float L1    = __builtin_amdgcn_logf(1.0f + p);            // log2
      float vv    = __builtin_amdgcn_logf(1.0f + (b2 * LN2) * L1);
      float y = (b1 * LN2) * vv + b5 * xv + b6 * x2 + b7 * x3 + b8 * x4;
      tG[e * TBL_STR + m] = y;
    }
  }
}

// ---------- phase 2: FUSED basis(table)+GEMM, counted-vmcnt tri-buffer ----------
#define BM 128
#define BN 512
#define BK 32                 // = 2 input-columns x 16 m
#define SPLITK 8
#define KC (K_DIM / SPLITK)   // 1024
#define NITER (KC / BK)       // 32 K-steps
#define XCOLS (KC / M_DIM)    // 64 x-columns per block

#define GLD16(g, l) \
  __builtin_amdgcn_global_load_lds((const __attribute__((address_space(1))) void*)(g), \
                                   (__attribute__((address_space(3))) void*)(l), 16, 0, 0)

// fused counted-wait + barrier in ONE asm: memory ops cannot cross ("memory"
// clobber), but register-only VALU/MFMA remain schedulable around it.
#define WAIT_BAR(N) \
  asm volatile("s_waitcnt vmcnt(" #N ") lgkmcnt(0)\n\ts_barrier" ::: "memory")

template <int ATOMIC>
__global__ __launch_bounds__(512, 2) void gemm_kernel(
    const float* __restrict__ x,      // [B_DIM][IN_DIM] fp32
    const ushort_t* __restrict__ Bt,  // coeffs bf16 [OUT_DIM][K_DIM]
    const float* __restrict__ tG,     // basis table [513][20] f32
    float* __restrict__ P) {          // partials [SPLITK][B][OUT] or out
  // LDS: As dbuf 16K + Bs TRIBUF 96K + table 40.1K = 152.1 KiB (1 block/CU)
  __shared__ __align__(16) ushort_t As[2][BM * BK];
  __shared__ __align__(16) ushort_t Bs[3][BN * BK];
  __shared__ __align__(16) float    Ts[TBL_F32];
  const int tid  = threadIdx.x;
  const int wave = tid >> 6;
  const int lane = tid & 63;
  const int wgid = blockIdx.x;
  const int ks = wgid & 7, bm = wgid >> 3;   // same-ks blocks -> same XCD, B-slice L2-hot

  // ---- table -> LDS (one-time; 2565 float4s across 512 threads) ----
  {
    const float4* g4 = (const float4*)tG;
    float4* l4 = (float4*)Ts;
    for (int i = tid; i < TBL_F32 / 4; i += 512) l4[i] = g4[i];
  }

  // ---- B staging: global_load_lds linear dest, pre-swizzled source slot ----
  const int srow = wave * 16 + (lane >> 2);
  const int scol = (((lane & 3) ^ ((lane >> 3) & 3)) * 8);
  const ushort_t* Bg0 = Bt + (size_t)srow * K_DIM + ks * KC + scol;
  const ushort_t* Bg1 = Bg0 + (size_t)128 * K_DIM;
  const ushort_t* Bg2 = Bg0 + (size_t)256 * K_DIM;
  const ushort_t* Bg3 = Bg0 + (size_t)384 * K_DIM;
  const int bofs0 = (wave * 16) * BK;
  const int bofs1 = (128 + wave * 16) * BK;
  const int bofs2 = (256 + wave * 16) * BK;
  const int bofs3 = (384 + wave * 16) * BK;

#define STAGEB(lb) do { \
    GLD16(Bg0, &Bs[lb][bofs0]); GLD16(Bg1, &Bs[lb][bofs1]); \
    GLD16(Bg2, &Bs[lb][bofs2]); GLD16(Bg3, &Bs[lb][bofs3]); \
    Bg0 += BK; Bg1 += BK; Bg2 += BK; Bg3 += BK; } while (0)

  // ---- basis production: thread -> (row, il, m-half); x via register prefetch ----
  const int half = wave & 1;                       // m in [half*8, half*8+8)
  const int arow = (wave >> 1) * 32 + (lane >> 1); // 0..127
  const int il   = lane & 1;                       // which of 2 input cols in BK
  const int aslot = ((il * 2 + half) ^ ((lane >> 2) & 3));  // XOR-swizzled 16B slot
  const int awe   = arow * BK + aslot * 8;
  const float* xg = x + (size_t)(bm * BM + arow) * IN_DIM + ks * XCOLS + il;
  const int thalf = half * 8;                      // f32 offset of this thread's m's

  // table interp: ~30 VALU, 4 ds_read_b128, ZERO transcendental (was 40 trans +
  // 160 VALU with a 5-deep serial trans chain — the r9 VALU/trans wall).
#define BASIS(ab, xv) do { \
    float uu = ((xv) - 0.1f) * TBL_INVH; \
    uu = fminf(fmaxf(uu, 0.0f), 511.99f); \
    float fi = floorf(uu); \
    float fr = uu - fi; \
    int tix = (int)fi * TBL_STR + thalf; \
    f32x4 v0 = *(const f32x4*)&Ts[tix]; \
    f32x4 v1 = *(const f32x4*)&Ts[tix + 4]; \
    f32x4 w0 = *(const f32x4*)&Ts[tix + TBL_STR]; \
    f32x4 w1 = *(const f32x4*)&Ts[tix + TBL_STR + 4]; \
    float ym[8]; \
    _Pragma("unroll") \
    for (int k = 0; k < 4; ++k) { \
      ym[k]     = v0[k] + fr * (w0[k] - v0[k]); \
      ym[4 + k] = v1[k] + fr * (w1[k] - v1[k]); \
    } \
    *(uint4*)(&As[ab][awe]) = make_uint4(pkbf(ym[0], ym[1]), pkbf(ym[2], ym[3]), \
                                         pkbf(ym[4], ym[5]), pkbf(ym[6], ym[7])); \
  } while (0)

  // ---- MFMA geometry: 8 waves as 2x4 grid of 64x128 wave-tiles ----
  const int wr = wave >> 2, wc = wave & 3;
  const int fm = lane & 15;
  const int fkswz = (((lane >> 4) ^ ((lane >> 1) & 3)) << 3);

  f32x4 acc[4][8] = {};

#define COMPUTE(ab, lb) do { \
    bf16x8 af[4], bfv[8]; \
    _Pragma("unroll") \
    for (int t2 = 0; t2 < 4; ++t2) \
      af[t2] = *(const bf16x8*)&As[ab][(wr * 64 + t2 * 16 + fm) * BK + fkswz]; \
    _Pragma("unroll") \
    for (int u = 0; u < 8; ++u) \
      bfv[u] = *(const bf16x8*)&Bs[lb][(wc * 128 + u * 16 + fm) * BK + fkswz]; \
    __builtin_amdgcn_s_setprio(1); \
    _Pragma("unroll") \
    for (int mt = 0; mt < 4; ++mt) \
      _Pragma("unroll") \
      for (int nt = 0; nt < 8; ++nt) \
        acc[mt][nt] = __builtin_amdgcn_mfma_f32_16x16x32_bf16(af[mt], bfv[nt], acc[mt][nt], 0, 0, 0); \
    __builtin_amdgcn_s_setprio(0); \
  } while (0)

  // one step: xn issued FIRST so the barrier's vmcnt(4) retires {batch t+1, xn}
  // exactly (induction: during step t outstanding = prev-batch(4)+xn(1)+new(4)=9;
  // vmcnt(4) retires 5 = batch t+1 + xn -> step t+1's Bs and x are both ready).
#define STEP(lbN, ap, ac, lb, t1) do { \
    float xc = xn; \
    xn = xg[2 * ((t1) + 1)]; \
    STAGEB(lbN); \
    BASIS(ap, xc); COMPUTE(ac, lb); WAIT_BAR(4); } while (0)

  // ---- prologue ----
  float x0 = xg[0];
  STAGEB(0); STAGEB(1);
  __syncthreads();              // table-LDS + Bs[0..1] + x0 all drained/visible
  float xn = xg[2];             // x for tile 1
  BASIS(0, x0);
  WAIT_BAR(0);                  // As[0] visible, xn retired

  // ---- main loop: 30 steps, statically unrolled x6 (lb period 3, As parity 2) ----
  for (int tb = 0; tb < NITER - 2; tb += 6) {
    STEP(2, 1, 0, 0, tb + 1);   // t = tb+0
    STEP(0, 0, 1, 1, tb + 2);   // t = tb+1
    STEP(1, 1, 0, 2, tb + 3);   // t = tb+2
    STEP(2, 0, 1, 0, tb + 4);   // t = tb+3
    STEP(0, 1, 0, 1, tb + 5);   // t = tb+4
    STEP(1, 0, 1, 2, tb + 6);   // t = tb+5
  }
  // ---- tail K-steps: t = 30, 31 (all 32 batches staged; xn = x for tile 31) ----
  BASIS(1, xn);
  COMPUTE(0, 0);                // t=30: As[0], Bs[30%3=0]
  WAIT_BAR(0);
  COMPUTE(1, 1);                // t=31: As[1], Bs[31%3=1]

  // ---- epilogue: C/D layout col = lane&15, row = (lane>>4)*4 + reg ----
  const int colb = wc * 128 + fm;
  const int rowb = bm * BM + wr * 64 + (lane >> 4) * 4;
  float* out = P + (ATOMIC ? (size_t)0 : (size_t)ks * MN);
  #pragma unroll
  for (int mt = 0; mt < 4; ++mt) {
    #pragma unroll
    for (int nt = 0; nt < 8; ++nt) {
      #pragma unroll
      for (int j = 0; j < 4; ++j) {
        int row = rowb + mt * 16 + j;
        int col = colb + nt * 16;
        float vv = acc[mt][nt][j];
        if (ATOMIC) atomicAdd(out + (size_t)row * OUT_DIM + col, vv);
        else        out[(size_t)row * OUT_DIM + col] = vv;
      }
    }
  }
#undef STAGEB
#undef BASIS
#undef COMPUTE
#undef STEP
}

// ---------- phase 3: reduce split-K partials ----------
__global__ __launch_bounds__(256) void reduce_kernel(
    const float* __restrict__ P, float* __restrict__ out) {
  int i = blockIdx.x * 256 + threadIdx.x;
  const float4* p = (const float4*)P;
  float4 r = p[i];
  #pragma unroll
  for (int s = 1; s < SPLITK; ++s) {
    float4 v = p[i + (size_t)s * (MN / 4)];
    r.x += v.x; r.y += v.y; r.z += v.z; r.w += v.w;
  }
  ((float4*)out)[i] = r;
}

extern "C" void kernel_launch(void* const* d_in, const int* in_sizes, int n_in,
                              void* d_out, int out_size, void* d_ws, size_t ws_size,
                              hipStream_t stream) {
  const float* x      = (const float*)d_in[0];   // [4096][512]
  const float* coeffs = (const float*)d_in[1];   // [512][512][16]
  const float* b_coef = (const float*)d_in[2];   // [16][8]
  float* out = (float*)d_out;
  char*  ws  = (char*)d_ws;

  const size_t COEF_BYTES = (size_t)OUT_DIM * K_DIM * 2;   // 8 MiB
  const size_t TBL_BYTES  = (size_t)TBL_F32 * 4;           // 41040 B (16B-aligned)
  ushort_t* coefb = (ushort_t*)ws;
  float*    tG    = (float*)(ws + COEF_BYTES);
  float* partials = (float*)(ws + COEF_BYTES + TBL_BYTES);
  const size_t FULL = COEF_BYTES + TBL_BYTES + (size_t)SPLITK * MN * 4;
  const bool use_atomic = (ws_size < FULL);   // deterministic per-session branch

  convert_coeffs_kernel<<<CONV_BLOCKS + 1, 256, 0, stream>>>(coeffs, coefb, b_coef, tG);

  const int nblk = (B_DIM / BM) * SPLITK;   // 32 x 8 = 256 blocks, 1/CU
  if (use_atomic) {
    hipMemsetAsync(d_out, 0, (size_t)MN * 4, stream);
    gemm_kernel<1><<<nblk, 512, 0, stream>>>(x, coefb, tG, out);
  } else {
    gemm_kernel<0><<<nblk, 512, 0, stream>>>(x, coefb, tG, partials);
    reduce_kernel<<<MN / 4 / 256, 256, 0, stream>>>(partials, out);
  }
}